// Round 1
// baseline (453.636 us; speedup 1.0000x reference)
//
#include <hip/hip_runtime.h>

// Network on 65536 points in a 64^3 grid.
// Key insight 1: _ln over a size-1 axis returns exactly its bias (zeros) ->
//   the whole KNN/attention branch contributes exactly 0; ctx channel 1 == 0.
// Key insight 2: nbr_interp is "prev point at cur_C[n]+off" -> replace the
//   191MB index-table read with a dense 72^3 (halo=4) grid of prev_F and a
//   9^3 stencil gather (grid is 1.42MB, L2-resident).

#define NPTS 65536
#define GD 72
#define GSX (GD*GD)           // 5184
#define GRID_FLOATS (GD*GD*GD) // 373248

__global__ __launch_bounds__(256) void k_scatter(const float* __restrict__ prev_F,
                                                 const int* __restrict__ prev_C,
                                                 float* __restrict__ grid) {
    int m = blockIdx.x * 256 + threadIdx.x;   // grid sized exactly N/256
    int x = prev_C[m*3+0], y = prev_C[m*3+1], z = prev_C[m*3+2];
    grid[(x+4)*GSX + (y+4)*GD + (z+4)] = prev_F[m];
}

// context[n] = b + sum_{dx,dy,dz in [-4,4]} grid[cur+off] * W_interp[k],
// k = ((dx+4)*9 + (dy+4))*9 + (dz+4). One wave per point; lane l covers
// k = l, l+64, ... (12 iters). Lane-consecutive k -> z-contiguous reads.
__global__ __launch_bounds__(256) void k_ctx(const int* __restrict__ cur_C,
                                             const float* __restrict__ grid,
                                             const float* __restrict__ W_interp,
                                             const float* __restrict__ b_interp,
                                             float* __restrict__ ctx) {
    int wid  = (blockIdx.x * 256 + threadIdx.x) >> 6;
    int lane = threadIdx.x & 63;
    int x = cur_C[wid*3+0], y = cur_C[wid*3+1], z = cur_C[wid*3+2];
    int base = x*GSX + y*GD + z;   // halo +4 cancels against off-4
    float acc = 0.f;
    for (int i = 0; i < 12; ++i) {
        int k = lane + (i << 6);
        if (k < 729) {
            int dx = k / 81;
            int r  = k - dx*81;
            int dy = r / 9;
            int dz = r - dy*9;
            acc = fmaf(grid[base + dx*GSX + dy*GD + dz], W_interp[k], acc);
        }
    }
    #pragma unroll
    for (int off = 32; off > 0; off >>= 1) acc += __shfl_xor(acc, off, 64);
    if (lane == 0) ctx[wid] = acc + b_interp[0];
}

// h = relu(conv3x3x3(ctx ch0, W_conv0[:,0,:]) + b); o = relu(h @ Wi00 + bi00)
__global__ __launch_bounds__(256) void k_conv0(const int* __restrict__ nbr3,
                                               const float* __restrict__ ctx,
                                               const float* __restrict__ W_conv0,
                                               const float* __restrict__ b_conv0,
                                               const float* __restrict__ Wi00,
                                               const float* __restrict__ bi00,
                                               float* __restrict__ h,
                                               float* __restrict__ o) {
    __shared__ int ln[256*27];
    int n0 = blockIdx.x * 256;
    for (int i = threadIdx.x; i < 256*27; i += 256) ln[i] = nbr3[n0*27 + i];
    __syncthreads();
    int n = n0 + threadIdx.x;
    float acc[32];
    #pragma unroll
    for (int d = 0; d < 32; ++d) acc[d] = b_conv0[d];
    for (int k = 0; k < 27; ++k) {
        int idx = ln[threadIdx.x*27 + k];
        float cv = 0.f;
        if (idx < NPTS) cv = ctx[idx];          // exec-masked gather
        #pragma unroll
        for (int d = 0; d < 32; ++d)            // W index wave-uniform -> s_load
            acc[d] = fmaf(cv, W_conv0[k*64 + d], acc[d]);
    }
    #pragma unroll
    for (int d = 0; d < 32; ++d) acc[d] = fmaxf(acc[d], 0.f);
    float4* hp = (float4*)(h + (size_t)n*32);
    #pragma unroll
    for (int q = 0; q < 8; ++q) hp[q] = make_float4(acc[q*4], acc[q*4+1], acc[q*4+2], acc[q*4+3]);
    float ov[8];
    #pragma unroll
    for (int j = 0; j < 8; ++j) {
        float t = bi00[j];
        #pragma unroll
        for (int d = 0; d < 32; ++d) t = fmaf(acc[d], Wi00[d*8 + j], t);
        ov[j] = fmaxf(t, 0.f);
    }
    float4* op = (float4*)(o + (size_t)n*8);
    op[0] = make_float4(ov[0], ov[1], ov[2], ov[3]);
    op[1] = make_float4(ov[4], ov[5], ov[6], ov[7]);
}

// o0a = relu(conv(o, Wi01)+bi01)   (8->8)
// o1a = relu(conv(h, Wi10)+bi10)   (32->8)
__global__ __launch_bounds__(256) void k_mid(const int* __restrict__ nbr3,
                                             const float* __restrict__ h,
                                             const float* __restrict__ o,
                                             const float* __restrict__ Wi01,
                                             const float* __restrict__ bi01,
                                             const float* __restrict__ Wi10,
                                             const float* __restrict__ bi10,
                                             float* __restrict__ o0a,
                                             float* __restrict__ o1a) {
    __shared__ int ln[256*27];
    int n0 = blockIdx.x * 256;
    for (int i = threadIdx.x; i < 256*27; i += 256) ln[i] = nbr3[n0*27 + i];
    __syncthreads();
    int n = n0 + threadIdx.x;
    float a0[8], a1[8];
    #pragma unroll
    for (int j = 0; j < 8; ++j) { a0[j] = bi01[j]; a1[j] = bi10[j]; }
    for (int k = 0; k < 27; ++k) {
        int idx = ln[threadIdx.x*27 + k];
        if (idx < NPTS) {                       // ~25% of neighbors present
            const float4* orow = (const float4*)(o + (size_t)idx*8);
            float4 oa = orow[0], ob = orow[1];
            float oc[8] = {oa.x, oa.y, oa.z, oa.w, ob.x, ob.y, ob.z, ob.w};
            #pragma unroll
            for (int c = 0; c < 8; ++c)
                #pragma unroll
                for (int j = 0; j < 8; ++j)
                    a0[j] = fmaf(oc[c], Wi01[(k*8+c)*8 + j], a0[j]);
            const float4* hrow = (const float4*)(h + (size_t)idx*32);
            #pragma unroll
            for (int q = 0; q < 8; ++q) {
                float4 hv = hrow[q];
                float hc[4] = {hv.x, hv.y, hv.z, hv.w};
                #pragma unroll
                for (int c = 0; c < 4; ++c)
                    #pragma unroll
                    for (int j = 0; j < 8; ++j)
                        a1[j] = fmaf(hc[c], Wi10[(k*32 + q*4 + c)*8 + j], a1[j]);
            }
        }
    }
    float4* p0 = (float4*)(o0a + (size_t)n*8);
    p0[0] = make_float4(fmaxf(a0[0],0.f), fmaxf(a0[1],0.f), fmaxf(a0[2],0.f), fmaxf(a0[3],0.f));
    p0[1] = make_float4(fmaxf(a0[4],0.f), fmaxf(a0[5],0.f), fmaxf(a0[6],0.f), fmaxf(a0[7],0.f));
    float4* p1 = (float4*)(o1a + (size_t)n*8);
    p1[0] = make_float4(fmaxf(a1[0],0.f), fmaxf(a1[1],0.f), fmaxf(a1[2],0.f), fmaxf(a1[3],0.f));
    p1[1] = make_float4(fmaxf(a1[4],0.f), fmaxf(a1[5],0.f), fmaxf(a1[6],0.f), fmaxf(a1[7],0.f));
}

// o1 = relu(conv(o1a, Wi11)+bi11) (8->16); o0 = relu(o0a@Wi02+bi02) (8->16)
// blk = [o0,o1] + h; out = relu(blk) @ W_conv1 + b_conv1
__global__ __launch_bounds__(256) void k_out(const int* __restrict__ nbr3,
                                             const float* __restrict__ h,
                                             const float* __restrict__ o0a,
                                             const float* __restrict__ o1a,
                                             const float* __restrict__ Wi11,
                                             const float* __restrict__ bi11,
                                             const float* __restrict__ Wi02,
                                             const float* __restrict__ bi02,
                                             const float* __restrict__ W_conv1,
                                             const float* __restrict__ b_conv1,
                                             float* __restrict__ out) {
    __shared__ int ln[256*27];
    int n0 = blockIdx.x * 256;
    for (int i = threadIdx.x; i < 256*27; i += 256) ln[i] = nbr3[n0*27 + i];
    __syncthreads();
    int n = n0 + threadIdx.x;
    float a1[16];
    #pragma unroll
    for (int j = 0; j < 16; ++j) a1[j] = bi11[j];
    for (int k = 0; k < 27; ++k) {
        int idx = ln[threadIdx.x*27 + k];
        if (idx < NPTS) {
            const float4* row = (const float4*)(o1a + (size_t)idx*8);
            float4 ra = row[0], rb = row[1];
            float rc[8] = {ra.x, ra.y, ra.z, ra.w, rb.x, rb.y, rb.z, rb.w};
            #pragma unroll
            for (int c = 0; c < 8; ++c)
                #pragma unroll
                for (int j = 0; j < 16; ++j)
                    a1[j] = fmaf(rc[c], Wi11[(k*8+c)*16 + j], a1[j]);
        }
    }
    float blk[32];
    {
        const float4* prow = (const float4*)(o0a + (size_t)n*8);
        float4 pa = prow[0], pb = prow[1];
        float pc[8] = {pa.x, pa.y, pa.z, pa.w, pb.x, pb.y, pb.z, pb.w};
        #pragma unroll
        for (int j = 0; j < 16; ++j) {
            float t = bi02[j];
            #pragma unroll
            for (int c = 0; c < 8; ++c) t = fmaf(pc[c], Wi02[c*16 + j], t);
            blk[j] = fmaxf(t, 0.f);
        }
    }
    #pragma unroll
    for (int j = 0; j < 16; ++j) blk[16+j] = fmaxf(a1[j], 0.f);
    const float4* hrow4 = (const float4*)(h + (size_t)n*32);
    #pragma unroll
    for (int q = 0; q < 8; ++q) {
        float4 hv = hrow4[q];
        blk[q*4+0] += hv.x; blk[q*4+1] += hv.y; blk[q*4+2] += hv.z; blk[q*4+3] += hv.w;
    }
    #pragma unroll
    for (int e = 0; e < 32; ++e) blk[e] = fmaxf(blk[e], 0.f);
    float acc[32];
    #pragma unroll
    for (int d = 0; d < 32; ++d) acc[d] = b_conv1[d];
    #pragma unroll
    for (int e = 0; e < 32; ++e)
        #pragma unroll
        for (int d = 0; d < 32; ++d)
            acc[d] = fmaf(blk[e], W_conv1[e*32 + d], acc[d]);
    float4* outp = (float4*)(out + (size_t)n*32);
    #pragma unroll
    for (int q = 0; q < 8; ++q) outp[q] = make_float4(acc[q*4], acc[q*4+1], acc[q*4+2], acc[q*4+3]);
}

extern "C" void kernel_launch(void* const* d_in, const int* in_sizes, int n_in,
                              void* d_out, int out_size, void* d_ws, size_t ws_size,
                              hipStream_t stream) {
    (void)in_sizes; (void)n_in; (void)out_size; (void)ws_size;
    const float* prev_F   = (const float*)d_in[0];
    const int*   prev_C   = (const int*)d_in[1];
    const int*   cur_C    = (const int*)d_in[2];
    // d_in[3] = nbr_interp  (unused: reconstructed via dense grid)
    const int*   nbr3     = (const int*)d_in[4];
    // d_in[5] = knn_idx     (unused: attention branch is exactly zero)
    const float* W_interp = (const float*)d_in[6];
    const float* b_interp = (const float*)d_in[7];
    const float* W_conv0  = (const float*)d_in[8];
    const float* b_conv0  = (const float*)d_in[9];
    const float* W_conv1  = (const float*)d_in[10];
    const float* b_conv1  = (const float*)d_in[11];
    const float* Wi00     = (const float*)d_in[12];
    const float* bi00     = (const float*)d_in[13];
    const float* Wi01     = (const float*)d_in[14];
    const float* bi01     = (const float*)d_in[15];
    const float* Wi02     = (const float*)d_in[16];
    const float* bi02     = (const float*)d_in[17];
    const float* Wi10     = (const float*)d_in[18];
    const float* bi10     = (const float*)d_in[19];
    const float* Wi11     = (const float*)d_in[20];
    const float* bi11     = (const float*)d_in[21];
    // d_in[22..33]: attention + LN params, all unused (branch == 0 exactly)

    float* ws   = (float*)d_ws;
    float* grid = ws;                       // 373248 floats (72^3)
    float* ctx  = ws + 373248;              // 65536
    float* h    = ws + 438784;              // 65536*32
    float* o    = ws + 2535936;             // 65536*8
    float* o0a  = ws + 3060224;             // 65536*8
    float* o1a  = ws + 3584512;             // 65536*8  (end: 4108800 floats = 15.7 MB)
    float* outp = (float*)d_out;

    hipMemsetAsync(grid, 0, GRID_FLOATS*sizeof(float), stream);  // ws is re-poisoned each call
    k_scatter<<<NPTS/256, 256, 0, stream>>>(prev_F, prev_C, grid);
    k_ctx    <<<NPTS/4,   256, 0, stream>>>(cur_C, grid, W_interp, b_interp, ctx);
    k_conv0  <<<NPTS/256, 256, 0, stream>>>(nbr3, ctx, W_conv0, b_conv0, Wi00, bi00, h, o);
    k_mid    <<<NPTS/256, 256, 0, stream>>>(nbr3, h, o, Wi01, bi01, Wi10, bi10, o0a, o1a);
    k_out    <<<NPTS/256, 256, 0, stream>>>(nbr3, h, o0a, o1a, Wi11, bi11, Wi02, bi02, W_conv1, b_conv1, outp);
}

// Round 3
// 447.756 us; speedup vs baseline: 1.0131x; 1.0131x over previous
//
#include <hip/hip_runtime.h>

// Network on 65536 points in a 64^3 grid.
// Key insight 1: _ln over a size-1 axis returns exactly its bias (zeros) ->
//   the whole KNN/attention branch contributes exactly 0; ctx channel 1 == 0.
// Key insight 2: nbr_interp is "prev point at cur_C[n]+off" -> replace the
//   191MB index table with a dense 72^3 (halo=4) grid of prev_F.
// Key insight 3 (this round): compute the 9^3 interp conv DENSELY over all
//   64^3 cells (4x redundant FLOPs but only ~1.2us of VALU) with LDS tiling
//   and wave-uniform weights, instead of 1.6M divergent 64-lane gathers
//   (TA address-serialization was the suspected ~100+us elephant). Results
//   scatter to per-point ctx via a dense cell->point-id inverse map.
// [Round 3 = round 2 resubmitted verbatim: round 2 hit GPUAcquisitionTimeout,
//  no measurement happened; keeping the kernel identical for clean A/B.]

#define NPTS 65536
#define GD 72
#define GSX (GD*GD)            // 5184
#define GRID_FLOATS (GD*GD*GD) // 373248
#define CD 64
#define CELLS (CD*CD*CD)       // 262144

__global__ __launch_bounds__(256) void k_scatter(const float* __restrict__ prev_F,
                                                 const int* __restrict__ prev_C,
                                                 const int* __restrict__ cur_C,
                                                 float* __restrict__ gridF,
                                                 int* __restrict__ pidg) {
    int m = blockIdx.x * 256 + threadIdx.x;   // grid sized exactly N/256
    int x = prev_C[m*3+0], y = prev_C[m*3+1], z = prev_C[m*3+2];
    gridF[(x+4)*GSX + (y+4)*GD + (z+4)] = prev_F[m];
    int cx = cur_C[m*3+0], cy = cur_C[m*3+1], cz = cur_C[m*3+2];
    pidg[(cx*CD + cy)*CD + cz] = m;           // inverse map (memset to -1)
}

// Dense 9x9x9 conv over the padded prev_F grid; write ctx[pid] at occupied
// cur cells. Block = 8x8x16 outputs, 256 threads, 4 z-outputs per thread.
// LDS input tile 16x16x24 floats (24.6KB). All weight loads wave-uniform.
__global__ __launch_bounds__(256) void k_ctx_dense(const float* __restrict__ gridF,
                                                   const int* __restrict__ pidg,
                                                   const float* __restrict__ W_interp,
                                                   const float* __restrict__ b_interp,
                                                   float* __restrict__ ctx) {
    __shared__ float tile[16*16*24];
    int bid = blockIdx.x;
    int bx = (bid >> 5) * 8, by = ((bid >> 2) & 7) * 8, bz = (bid & 3) * 16;
    int t = threadIdx.x;
    for (int i = t; i < 16*16*24; i += 256) {       // coalesced-ish staging (L2 hits)
        int a = i / (16*24);
        int r = i - a*(16*24);
        int b = r / 24;
        int c = r - b*24;
        tile[i] = gridF[(bx + a)*GSX + (by + b)*GD + (bz + c)];
    }
    __syncthreads();
    int tz = (t & 3) * 4;          // this thread's z window base: outputs z..z+3
    int ty = (t >> 2) & 7;
    int tx = t >> 5;
    float acc0 = 0.f, acc1 = 0.f, acc2 = 0.f, acc3 = 0.f;
    for (int dx = 0; dx < 9; ++dx) {
        for (int dy = 0; dy < 9; ++dy) {
            const float* row = &tile[((tx + dx)*16 + (ty + dy))*24 + tz];
            float4 r0 = *(const float4*)(row);      // 16B-aligned: stride 24, tz%4==0
            float4 r1 = *(const float4*)(row + 4);
            float4 r2 = *(const float4*)(row + 8);
            float v[12] = {r0.x,r0.y,r0.z,r0.w, r1.x,r1.y,r1.z,r1.w, r2.x,r2.y,r2.z,r2.w};
            const float* wp = &W_interp[(dx*9 + dy)*9];
            #pragma unroll
            for (int dz = 0; dz < 9; ++dz) {
                float w = wp[dz];                   // wave-uniform -> s_load
                acc0 = fmaf(v[dz+0], w, acc0);
                acc1 = fmaf(v[dz+1], w, acc1);
                acc2 = fmaf(v[dz+2], w, acc2);
                acc3 = fmaf(v[dz+3], w, acc3);
            }
        }
    }
    float bi = b_interp[0];
    int cell = ((bx + tx)*CD + (by + ty))*CD + (bz + tz);
    int4 pids = *(const int4*)(pidg + cell);        // cell%4==0 -> aligned
    if (pids.x >= 0) ctx[pids.x] = acc0 + bi;
    if (pids.y >= 0) ctx[pids.y] = acc1 + bi;
    if (pids.z >= 0) ctx[pids.z] = acc2 + bi;
    if (pids.w >= 0) ctx[pids.w] = acc3 + bi;
}

// h = relu(conv3x3x3(ctx ch0, W_conv0[:,0,:]) + b); o = relu(h @ Wi00 + bi00)
__global__ __launch_bounds__(256) void k_conv0(const int* __restrict__ nbr3,
                                               const float* __restrict__ ctx,
                                               const float* __restrict__ W_conv0,
                                               const float* __restrict__ b_conv0,
                                               const float* __restrict__ Wi00,
                                               const float* __restrict__ bi00,
                                               float* __restrict__ h,
                                               float* __restrict__ o) {
    __shared__ int ln[256*27];
    int n0 = blockIdx.x * 256;
    for (int i = threadIdx.x; i < 256*27; i += 256) ln[i] = nbr3[n0*27 + i];
    __syncthreads();
    int n = n0 + threadIdx.x;
    float acc[32];
    #pragma unroll
    for (int d = 0; d < 32; ++d) acc[d] = b_conv0[d];
    for (int k = 0; k < 27; ++k) {
        int idx = ln[threadIdx.x*27 + k];
        float cv = 0.f;
        if (idx < NPTS) cv = ctx[idx];          // exec-masked gather
        #pragma unroll
        for (int d = 0; d < 32; ++d)            // W index wave-uniform -> s_load
            acc[d] = fmaf(cv, W_conv0[k*64 + d], acc[d]);
    }
    #pragma unroll
    for (int d = 0; d < 32; ++d) acc[d] = fmaxf(acc[d], 0.f);
    float4* hp = (float4*)(h + (size_t)n*32);
    #pragma unroll
    for (int q = 0; q < 8; ++q) hp[q] = make_float4(acc[q*4], acc[q*4+1], acc[q*4+2], acc[q*4+3]);
    float ov[8];
    #pragma unroll
    for (int j = 0; j < 8; ++j) {
        float t = bi00[j];
        #pragma unroll
        for (int d = 0; d < 32; ++d) t = fmaf(acc[d], Wi00[d*8 + j], t);
        ov[j] = fmaxf(t, 0.f);
    }
    float4* op = (float4*)(o + (size_t)n*8);
    op[0] = make_float4(ov[0], ov[1], ov[2], ov[3]);
    op[1] = make_float4(ov[4], ov[5], ov[6], ov[7]);
}

// o0a = relu(conv(o, Wi01)+bi01)   (8->8)
// o1a = relu(conv(h, Wi10)+bi10)   (32->8)
__global__ __launch_bounds__(256) void k_mid(const int* __restrict__ nbr3,
                                             const float* __restrict__ h,
                                             const float* __restrict__ o,
                                             const float* __restrict__ Wi01,
                                             const float* __restrict__ bi01,
                                             const float* __restrict__ Wi10,
                                             const float* __restrict__ bi10,
                                             float* __restrict__ o0a,
                                             float* __restrict__ o1a) {
    __shared__ int ln[256*27];
    int n0 = blockIdx.x * 256;
    for (int i = threadIdx.x; i < 256*27; i += 256) ln[i] = nbr3[n0*27 + i];
    __syncthreads();
    int n = n0 + threadIdx.x;
    float a0[8], a1[8];
    #pragma unroll
    for (int j = 0; j < 8; ++j) { a0[j] = bi01[j]; a1[j] = bi10[j]; }
    for (int k = 0; k < 27; ++k) {
        int idx = ln[threadIdx.x*27 + k];
        if (idx < NPTS) {                       // ~29% of neighbors present
            const float4* orow = (const float4*)(o + (size_t)idx*8);
            float4 oa = orow[0], ob = orow[1];
            float oc[8] = {oa.x, oa.y, oa.z, oa.w, ob.x, ob.y, ob.z, ob.w};
            #pragma unroll
            for (int c = 0; c < 8; ++c)
                #pragma unroll
                for (int j = 0; j < 8; ++j)
                    a0[j] = fmaf(oc[c], Wi01[(k*8+c)*8 + j], a0[j]);
            const float4* hrow = (const float4*)(h + (size_t)idx*32);
            #pragma unroll
            for (int q = 0; q < 8; ++q) {
                float4 hv = hrow[q];
                float hc[4] = {hv.x, hv.y, hv.z, hv.w};
                #pragma unroll
                for (int c = 0; c < 4; ++c)
                    #pragma unroll
                    for (int j = 0; j < 8; ++j)
                        a1[j] = fmaf(hc[c], Wi10[(k*32 + q*4 + c)*8 + j], a1[j]);
            }
        }
    }
    float4* p0 = (float4*)(o0a + (size_t)n*8);
    p0[0] = make_float4(fmaxf(a0[0],0.f), fmaxf(a0[1],0.f), fmaxf(a0[2],0.f), fmaxf(a0[3],0.f));
    p0[1] = make_float4(fmaxf(a0[4],0.f), fmaxf(a0[5],0.f), fmaxf(a0[6],0.f), fmaxf(a0[7],0.f));
    float4* p1 = (float4*)(o1a + (size_t)n*8);
    p1[0] = make_float4(fmaxf(a1[0],0.f), fmaxf(a1[1],0.f), fmaxf(a1[2],0.f), fmaxf(a1[3],0.f));
    p1[1] = make_float4(fmaxf(a1[4],0.f), fmaxf(a1[5],0.f), fmaxf(a1[6],0.f), fmaxf(a1[7],0.f));
}

// o1 = relu(conv(o1a, Wi11)+bi11) (8->16); o0 = relu(o0a@Wi02+bi02) (8->16)
// blk = [o0,o1] + h; out = relu(blk) @ W_conv1 + b_conv1
__global__ __launch_bounds__(256) void k_out(const int* __restrict__ nbr3,
                                             const float* __restrict__ h,
                                             const float* __restrict__ o0a,
                                             const float* __restrict__ o1a,
                                             const float* __restrict__ Wi11,
                                             const float* __restrict__ bi11,
                                             const float* __restrict__ Wi02,
                                             const float* __restrict__ bi02,
                                             const float* __restrict__ W_conv1,
                                             const float* __restrict__ b_conv1,
                                             float* __restrict__ out) {
    __shared__ int ln[256*27];
    int n0 = blockIdx.x * 256;
    for (int i = threadIdx.x; i < 256*27; i += 256) ln[i] = nbr3[n0*27 + i];
    __syncthreads();
    int n = n0 + threadIdx.x;
    float a1[16];
    #pragma unroll
    for (int j = 0; j < 16; ++j) a1[j] = bi11[j];
    for (int k = 0; k < 27; ++k) {
        int idx = ln[threadIdx.x*27 + k];
        if (idx < NPTS) {
            const float4* row = (const float4*)(o1a + (size_t)idx*8);
            float4 ra = row[0], rb = row[1];
            float rc[8] = {ra.x, ra.y, ra.z, ra.w, rb.x, rb.y, rb.z, rb.w};
            #pragma unroll
            for (int c = 0; c < 8; ++c)
                #pragma unroll
                for (int j = 0; j < 16; ++j)
                    a1[j] = fmaf(rc[c], Wi11[(k*8+c)*16 + j], a1[j]);
        }
    }
    float blk[32];
    {
        const float4* prow = (const float4*)(o0a + (size_t)n*8);
        float4 pa = prow[0], pb = prow[1];
        float pc[8] = {pa.x, pa.y, pa.z, pa.w, pb.x, pb.y, pb.z, pb.w};
        #pragma unroll
        for (int j = 0; j < 16; ++j) {
            float t = bi02[j];
            #pragma unroll
            for (int c = 0; c < 8; ++c) t = fmaf(pc[c], Wi02[c*16 + j], t);
            blk[j] = fmaxf(t, 0.f);
        }
    }
    #pragma unroll
    for (int j = 0; j < 16; ++j) blk[16+j] = fmaxf(a1[j], 0.f);
    const float4* hrow4 = (const float4*)(h + (size_t)n*32);
    #pragma unroll
    for (int q = 0; q < 8; ++q) {
        float4 hv = hrow4[q];
        blk[q*4+0] += hv.x; blk[q*4+1] += hv.y; blk[q*4+2] += hv.z; blk[q*4+3] += hv.w;
    }
    #pragma unroll
    for (int e = 0; e < 32; ++e) blk[e] = fmaxf(blk[e], 0.f);
    float acc[32];
    #pragma unroll
    for (int d = 0; d < 32; ++d) acc[d] = b_conv1[d];
    #pragma unroll
    for (int e = 0; e < 32; ++e)
        #pragma unroll
        for (int d = 0; d < 32; ++d)
            acc[d] = fmaf(blk[e], W_conv1[e*32 + d], acc[d]);
    float4* outp = (float4*)(out + (size_t)n*32);
    #pragma unroll
    for (int q = 0; q < 8; ++q) outp[q] = make_float4(acc[q*4], acc[q*4+1], acc[q*4+2], acc[q*4+3]);
}

extern "C" void kernel_launch(void* const* d_in, const int* in_sizes, int n_in,
                              void* d_out, int out_size, void* d_ws, size_t ws_size,
                              hipStream_t stream) {
    (void)in_sizes; (void)n_in; (void)out_size; (void)ws_size;
    const float* prev_F   = (const float*)d_in[0];
    const int*   prev_C   = (const int*)d_in[1];
    const int*   cur_C    = (const int*)d_in[2];
    // d_in[3] = nbr_interp  (unused: reconstructed via dense grid)
    const int*   nbr3     = (const int*)d_in[4];
    // d_in[5] = knn_idx     (unused: attention branch is exactly zero)
    const float* W_interp = (const float*)d_in[6];
    const float* b_interp = (const float*)d_in[7];
    const float* W_conv0  = (const float*)d_in[8];
    const float* b_conv0  = (const float*)d_in[9];
    const float* W_conv1  = (const float*)d_in[10];
    const float* b_conv1  = (const float*)d_in[11];
    const float* Wi00     = (const float*)d_in[12];
    const float* bi00     = (const float*)d_in[13];
    const float* Wi01     = (const float*)d_in[14];
    const float* bi01     = (const float*)d_in[15];
    const float* Wi02     = (const float*)d_in[16];
    const float* bi02     = (const float*)d_in[17];
    const float* Wi10     = (const float*)d_in[18];
    const float* bi10     = (const float*)d_in[19];
    const float* Wi11     = (const float*)d_in[20];
    const float* bi11     = (const float*)d_in[21];
    // d_in[22..33]: attention + LN params, all unused (branch == 0 exactly)

    float* ws    = (float*)d_ws;
    float* gridF = ws;                      // 373248 floats (72^3)
    int*   pidg  = (int*)(ws + 373248);     // 262144 ints (64^3 cell -> point id)
    float* ctx   = ws + 635392;             // 65536
    float* h     = ws + 700928;             // 65536*32
    float* o     = ws + 2798080;            // 65536*8
    float* o0a   = ws + 3322368;            // 65536*8
    float* o1a   = ws + 3846656;            // 65536*8  (end: 4370944 floats = 16.7 MB)
    float* outp  = (float*)d_out;

    hipMemsetAsync(gridF, 0,    GRID_FLOATS*sizeof(float), stream);
    hipMemsetAsync(pidg,  0xFF, CELLS*sizeof(int),         stream);   // -1
    k_scatter  <<<NPTS/256, 256, 0, stream>>>(prev_F, prev_C, cur_C, gridF, pidg);
    k_ctx_dense<<<256,      256, 0, stream>>>(gridF, pidg, W_interp, b_interp, ctx);
    k_conv0    <<<NPTS/256, 256, 0, stream>>>(nbr3, ctx, W_conv0, b_conv0, Wi00, bi00, h, o);
    k_mid      <<<NPTS/256, 256, 0, stream>>>(nbr3, h, o, Wi01, bi01, Wi10, bi10, o0a, o1a);
    k_out      <<<NPTS/256, 256, 0, stream>>>(nbr3, h, o0a, o1a, Wi11, bi11, Wi02, bi02, W_conv1, b_conv1, outp);
}